// Round 7
// baseline (1540.917 us; speedup 1.0000x reference)
//
#include <hip/hip_runtime.h>

typedef _Float16 f16;
typedef __attribute__((ext_vector_type(4))) _Float16 f16x4;
typedef __attribute__((ext_vector_type(8))) _Float16 f16x8;
typedef __attribute__((ext_vector_type(4))) float f32x4;

// ---------------------------------------------------------------- helpers
__device__ __forceinline__ float fast_sig(float x) { return 1.f / (1.f + __expf(-x)); }
// tanh via 1 - 2/(e^{2x}+1): saturates cleanly to +/-1, no NaN at extremes
__device__ __forceinline__ float fast_tanh(float x) {
  float e = __expf(2.f * x);
  return 1.f - 2.f / (e + 1.f);
}

// ---------------------------------------------------------------- f32 -> f16 convert
__global__ __launch_bounds__(256) void f2h_kernel(const float* __restrict__ src,
                                                  f16* __restrict__ dst) {
  size_t i = ((size_t)blockIdx.x * 256 + threadIdx.x) * 4;
  float4 v = *(const float4*)(src + i);
  dst[i + 0] = (f16)v.x;
  dst[i + 1] = (f16)v.y;
  dst[i + 2] = (f16)v.z;
  dst[i + 3] = (f16)v.w;
}

// gather embedding rows: xg[m,:] = (f16)emb[ids[m],:]   (one block per m, H=1024)
__global__ __launch_bounds__(256) void gather_rows(const float* __restrict__ emb,
                                                   const int* __restrict__ ids,
                                                   f16* __restrict__ xg) {
  int m = blockIdx.x;
  int i = threadIdx.x * 4;
  const float* src = emb + (size_t)ids[m] * 1024 + i;
  float4 v = *(const float4*)src;
  f16* d = xg + (size_t)m * 1024 + i;
  d[0] = (f16)v.x; d[1] = (f16)v.y; d[2] = (f16)v.z; d[3] = (f16)v.w;
}

// ---------------------------------------------------------------- h-state init + flag reset
__global__ __launch_bounds__(256) void init_h(const float* __restrict__ h0,
                                              f16* __restrict__ h1slot0,
                                              f16* __restrict__ h2slot0,
                                              unsigned* __restrict__ flags) {
  int i = blockIdx.x * 256 + threadIdx.x;  // grid 256 -> 65536
  h1slot0[i] = (f16)h0[i];
  h2slot0[i] = (f16)h0[65536 + i];
  if (i < 8192) flags[i] = 0;  // 256 block-flags + 8 go-lines, all 64B-padded
}

// ---------------------------------------------------------------- persistent 2-layer LSTM
// One cooperative launch runs all 64 timesteps. 256 blocks x 512 threads (8 waves),
// block p owns hidden units [4p,4p+4) of BOTH layers: 16 gate-rows x 4 matrices
// (Wih1,Whh1,Wih2,Whh2) = 128 KB f16 staged into LDS ONCE.
// Phase t computes layer1_t and layer2_{t-1} in one merged pass.
// Cost evolution (measured, per phase): cg::grid.sync ~46us; LLC atomic counter
// ~24us; 256-wide flag poll ~22us; +batched loads ~15.4us; +cached write-once
// h reads ~14.6us. Fit across all rounds: compute+loads ~2us, BARRIER ~13us.
//   R2 floor = publish side (256 serialized same-line RMWs ~180cy each).
//   R3-R6 floor = poll side (every block polls all 256 flags -> 65K LLC
//   requests/round, saturating the fabric AND contending with stragglers).
// THIS version: leader-gather barrier. Parallel publish (256 distinct-line
// stores, no RMW) + ONLY block 0 gathers the 256 flags, then publishes the
// epoch to 8 replicated 64B go-lines; every other block's wave0 polls ONE
// go-line with all 64 lanes on the same address (one coalesced request/round).
// Waiting traffic: 65536 -> ~255 requests/round.
// h data: writes agent-scope sc1 into WRITE-ONCE history slots (never stale in
// any L2); reads normal cached loads (verified R6). Ordering chain is
// LLC-transitive: h stores drain at __syncthreads -> flag -> leader -> go ->
// reader's cold h fetch.
__global__ __launch_bounds__(512, 1) void lstm_persistent(
    const float* __restrict__ w_ih, const float* __restrict__ w_hh,  // [2][4096][1024] f32
    const float* __restrict__ b_ih, const float* __restrict__ b_hh,  // [2][4096] f32
    const float* __restrict__ c0,                                    // [2][64][1024] f32
    const f16* __restrict__ xg,                                      // [4096][1024] f16
    f16* __restrict__ h1hist,                                        // 65 slots (slot0 = init)
    f16* __restrict__ h2hist,                                        // 65 slots (slot0 = init)
    float* __restrict__ hf, float* __restrict__ cf,                  // [2][64][1024] f32
    unsigned* __restrict__ flags) {  // [256] block-flags + [8] go-lines, stride-16 u32
  __shared__ f16 wlds[65536];               // 4 matrices x 2048 slots x 8 f16 = 128 KB
  __shared__ float red1[2048], red2[2048];  // [wave][16m][16n] partials, 8 KB each
  __shared__ float bsum[32];                // b_ih+b_hh for this block's 16 rows x 2 layers
  const int p = blockIdx.x;
  const int tid = threadIdx.x;
  const int lane = tid & 63, w = tid >> 6;
  const int mt = w & 3, kh = w >> 2;        // wave = (batch-tile, K-half)
  const int am = mt * 16 + (lane & 15);     // A-fragment batch row
  const int kq = (lane >> 4) * 8;

  // ---- one-time staging: 8192 slots / 512 threads = 16 each
  for (int s = tid; s < 8192; s += 512) {
    const int mat = s >> 11, sl = s & 2047;       // mat: 0=Wih1 1=Whh1 2=Wih2 3=Whh2
    const int ln = sl & 63, ks = sl >> 6;
    const int n = ln & 15;                        // n = gate*4 + unit_local
    const int row = (n >> 2) * 1024 + p * 4 + (n & 3) + ((mat >= 2) ? 4096 : 0);
    const int k = ks * 32 + (ln >> 4) * 8;
    const float* src = ((mat & 1) ? w_hh : w_ih) + (size_t)row * 1024 + k;
    float4 v0 = *(const float4*)src;
    float4 v1 = *(const float4*)(src + 4);
    f16x8 hv = {(f16)v0.x, (f16)v0.y, (f16)v0.z, (f16)v0.w,
                (f16)v1.x, (f16)v1.y, (f16)v1.z, (f16)v1.w};
    *(f16x8*)(wlds + (size_t)mat * 16384 + (size_t)sl * 8) = hv;
  }
  if (tid < 32) {
    int l = tid >> 4, n = tid & 15;
    int row = l * 4096 + (n >> 2) * 1024 + p * 4 + (n & 3);
    bsum[tid] = b_ih[row] + b_hh[row];
  }
  float creg;
  {
    int q = tid & 255;
    size_t idx = (size_t)(q >> 2) * 1024 + p * 4 + (q & 3);
    creg = (tid < 256) ? c0[idx] : c0[65536 + idx];
  }
  __syncthreads();

  for (int t = 0; t <= 64; ++t) {
    // clamped addresses so edge phases stay straight-line (MFMA predicated off)
    const int tx = (t < 64) ? t : 63;
    const int t2 = (t > 0) ? t - 1 : 0;
    // per-lane k-base for this wave: k = ks*32 + kq, ks in [kh*16, kh*16+16)
    const f16* xrow  = xg + ((size_t)tx * 64 + am) * 1024 + kh * 512 + kq;
    const f16* hrow  = h1hist + ((size_t)t * 64 + am) * 1024 + kh * 512 + kq;   // h1_{t-1}
    const f16* h2row = h2hist + ((size_t)t2 * 64 + am) * 1024 + kh * 512 + kq;  // h2_{t-2}

    f32x4 acc1 = {0.f, 0.f, 0.f, 0.f};
    f32x4 acc2 = {0.f, 0.f, 0.f, 0.f};
    // h reads: NORMAL cached loads (write-once slot addresses -> never stale).
#pragma unroll
    for (int i = 0; i < 16; ++i) {
      const int ks = kh * 16 + i;
      f16x8 xv  = *(const f16x8*)(xrow + i * 32);
      f16x8 hv  = *(const f16x8*)(hrow + i * 32);
      f16x8 h2v = *(const f16x8*)(h2row + i * 32);
      f16x8 b0 = *(const f16x8*)(wlds + (size_t)ks * 512 + lane * 8);
      f16x8 b1 = *(const f16x8*)(wlds + 16384 + (size_t)ks * 512 + lane * 8);
      f16x8 b2 = *(const f16x8*)(wlds + 32768 + (size_t)ks * 512 + lane * 8);
      f16x8 b3 = *(const f16x8*)(wlds + 49152 + (size_t)ks * 512 + lane * 8);
      if (t < 64) {  // layer-1 gates, timestep t
        acc1 = __builtin_amdgcn_mfma_f32_16x16x32_f16(xv, b0, acc1, 0, 0, 0);
        acc1 = __builtin_amdgcn_mfma_f32_16x16x32_f16(hv, b1, acc1, 0, 0, 0);
      }
      if (t > 0) {   // layer-2 gates, timestep t-1
        acc2 = __builtin_amdgcn_mfma_f32_16x16x32_f16(hv, b2, acc2, 0, 0, 0);
        acc2 = __builtin_amdgcn_mfma_f32_16x16x32_f16(h2v, b3, acc2, 0, 0, 0);
      }
    }

    if (t < 64) {
#pragma unroll
      for (int q = 0; q < 4; q++)
        red1[w * 256 + ((lane >> 4) * 4 + q) * 16 + (lane & 15)] = acc1[q];
    }
    if (t > 0) {
#pragma unroll
      for (int q = 0; q < 4; q++)
        red2[w * 256 + ((lane >> 4) * 4 + q) * 16 + (lane & 15)] = acc2[q];
    }
    __syncthreads();

    // ---- elementwise: threads 0-255 -> layer1, 256-511 -> layer2
    if (t < 64 && tid < 256) {
      const int b = tid >> 2, ul = tid & 3;
      const int mrow = (b & 15) * 16, mtb = (b >> 4) * 256;
      float g4[4];
#pragma unroll
      for (int g = 0; g < 4; g++) {
        int n = g * 4 + ul;
        g4[g] = red1[mtb + mrow + n] + red1[1024 + mtb + mrow + n] + bsum[n];
      }
      float cn = fast_sig(g4[1]) * creg + fast_sig(g4[0]) * fast_tanh(g4[2]);
      float hn = fast_sig(g4[3]) * fast_tanh(cn);
      creg = cn;
      const int u = p * 4 + ul;
      if (t == 63) {
        hf[(size_t)b * 1024 + u] = hn;
        cf[(size_t)b * 1024 + u] = cn;
      }
      // pack 4 units (ul=0..3, same wave) -> one 8B agent-scope store
      float h1v = __shfl_down(hn, 1, 64);
      float h2s = __shfl_down(hn, 2, 64);
      float h3v = __shfl_down(hn, 3, 64);
      if (ul == 0) {
        union { f16x4 h; unsigned long long u64; } pk;
        pk.h = (f16x4){(f16)hn, (f16)h1v, (f16)h2s, (f16)h3v};
        f16* dst = h1hist + (size_t)(t + 1) * 65536 + (size_t)b * 1024 + p * 4;
        __hip_atomic_store((unsigned long long*)dst, pk.u64,
                           __ATOMIC_RELAXED, __HIP_MEMORY_SCOPE_AGENT);
      }
    }
    if (t > 0 && tid >= 256) {
      const int q = tid & 255;
      const int b = q >> 2, ul = q & 3;
      const int mrow = (b & 15) * 16, mtb = (b >> 4) * 256;
      float g4[4];
#pragma unroll
      for (int g = 0; g < 4; g++) {
        int n = g * 4 + ul;
        g4[g] = red2[mtb + mrow + n] + red2[1024 + mtb + mrow + n] + bsum[16 + n];
      }
      float cn = fast_sig(g4[1]) * creg + fast_sig(g4[0]) * fast_tanh(g4[2]);
      float hn = fast_sig(g4[3]) * fast_tanh(cn);
      creg = cn;
      const int u = p * 4 + ul;
      if (t == 64) {
        hf[65536 + (size_t)b * 1024 + u] = hn;
        cf[65536 + (size_t)b * 1024 + u] = cn;
      }
      float h1v = __shfl_down(hn, 1, 64);
      float h2s = __shfl_down(hn, 2, 64);
      float h3v = __shfl_down(hn, 3, 64);
      if (ul == 0) {
        union { f16x4 h; unsigned long long u64; } pk;
        pk.h = (f16x4){(f16)hn, (f16)h1v, (f16)h2s, (f16)h3v};
        f16* dst = h2hist + (size_t)t * 65536 + (size_t)b * 1024 + p * 4;
        __hip_atomic_store((unsigned long long*)dst, pk.u64,
                           __ATOMIC_RELAXED, __HIP_MEMORY_SCOPE_AGENT);
      }
    }

    if (t < 64) {
      // ---- leader-gather barrier ----
      // __syncthreads drains each wave's vmcnt -> all sc1 h-stores at LLC.
      __syncthreads();
      const unsigned epoch = (unsigned)(t + 1);
      if (w == 0) {
        if (lane == 0)
          __hip_atomic_store(flags + (size_t)p * 16, epoch,
                             __ATOMIC_RELAXED, __HIP_MEMORY_SCOPE_AGENT);
        if (p == 0) {
          // leader: gather all 256 flags (4 per lane, distinct padded lines)
          for (;;) {
            bool ok = true;
#pragma unroll
            for (int j = 0; j < 4; j++) {
              unsigned v = __hip_atomic_load(flags + (size_t)(lane * 4 + j) * 16,
                                             __ATOMIC_RELAXED, __HIP_MEMORY_SCOPE_AGENT);
              ok &= (v >= epoch);
            }
            if (__all(ok)) break;
            __builtin_amdgcn_s_sleep(1);
          }
          // publish epoch to 8 replicated go-lines (64B-padded)
          if (lane < 8)
            __hip_atomic_store(flags + 4096 + (size_t)lane * 16, epoch,
                               __ATOMIC_RELAXED, __HIP_MEMORY_SCOPE_AGENT);
        } else {
          // wait on ONE go-line; all 64 lanes read the same address -> one
          // coalesced request per round. 32 blocks share each go-line.
          const unsigned* go = flags + 4096 + (size_t)(p & 7) * 16;
          for (;;) {
            unsigned v = __hip_atomic_load(go, __ATOMIC_RELAXED,
                                           __HIP_MEMORY_SCOPE_AGENT);
            if (__all(v >= epoch)) break;
            __builtin_amdgcn_s_sleep(1);
          }
        }
      }
      __syncthreads();
    }
  }
}

// ---------------------------------------------------------------- simple direct-global GEMM
// C[m,n] = sum_k A[m,k]*B[n,k] (+bias1+bias2)(tanh). A = A1 rows [*,K1] then A2 for k>=K1.
// B row-major [N, Ktot], all f16. Block = 64x64 tile, 4 waves; wave w owns 16 m-rows.
template <typename OutT>
__global__ __launch_bounds__(256) void gemm_simple(
    const f16* __restrict__ A1, const f16* __restrict__ A2,
    const f16* __restrict__ Bm,
    const float* __restrict__ bias1, const float* __restrict__ bias2,
    OutT* __restrict__ C, int ldc,
    int K1, int Ktot, int do_tanh) {
  const int tid = threadIdx.x;
  const int lane = tid & 63;
  const int w = tid >> 6;
  const int m0 = blockIdx.y * 64 + w * 16;  // this wave's 16 m-rows
  const int n0 = blockIdx.x * 64;
  const int am = m0 + (lane & 15);
  const int kq = (lane >> 4) * 8;           // quad's k-offset within a 32-chunk
  const int K2 = Ktot - K1;

  f32x4 acc[4];
#pragma unroll
  for (int j = 0; j < 4; j++) acc[j] = (f32x4){0.f, 0.f, 0.f, 0.f};

  for (int k0 = 0; k0 < Ktot; k0 += 32) {
    int k = k0 + kq;
    f16x8 av;
    if (k < K1)
      av = *(const f16x8*)(A1 + (size_t)am * K1 + k);
    else
      av = *(const f16x8*)(A2 + (size_t)am * K2 + (k - K1));
#pragma unroll
    for (int j = 0; j < 4; j++) {
      f16x8 bv = *(const f16x8*)(Bm + (size_t)(n0 + j * 16 + (lane & 15)) * Ktot + k);
      acc[j] = __builtin_amdgcn_mfma_f32_16x16x32_f16(av, bv, acc[j], 0, 0, 0);
    }
  }

  const int r0 = (lane >> 4) * 4;
  const int cc = lane & 15;
#pragma unroll
  for (int j = 0; j < 4; j++) {
    int col = n0 + j * 16 + cc;
    float bv = 0.f;
    if (bias1) bv += bias1[col];
    if (bias2) bv += bias2[col];
#pragma unroll
    for (int q = 0; q < 4; q++) {
      float v = acc[j][q] + bv;
      if (do_tanh) v = fast_tanh(v);
      C[(size_t)(m0 + r0 + q) * ldc + col] = (OutT)v;
    }
  }
}

// ---------------------------------------------------------------- attention scores/softmax/wc
// one block per (t,b): scores[s] = ctx[s,b,:].q ; softmax ; wc = a @ ctx[:,b,:]
__global__ __launch_bounds__(256) void attn_kernel(
    const float* __restrict__ Q,   // [4096][1024] f32
    const float* __restrict__ ctx, // context f32 [S=64][B=64][H=1024]
    f16* __restrict__ wc,          // [4096][1024] f16
    float* __restrict__ attn_out) {// [64][64] (t==63 only)
  const int m = blockIdx.x;
  const int b = m & 63;
  const int t = m >> 6;
  const int tid = threadIdx.x;
  const int lane = tid & 63;
  const int w = tid >> 6;
  __shared__ float s_sc[64];
  __shared__ float s_at[64];

  const float* qp = Q + (size_t)m * 1024 + lane * 16;
  float qf[16];
#pragma unroll
  for (int i = 0; i < 4; i++) {
    float4 v = *(const float4*)(qp + i * 4);
    qf[i * 4 + 0] = v.x; qf[i * 4 + 1] = v.y; qf[i * 4 + 2] = v.z; qf[i * 4 + 3] = v.w;
  }

  // scores: wave w handles s in [w*16, w*16+16)
  for (int si = 0; si < 16; si++) {
    int s = w * 16 + si;
    const float* cp = ctx + ((size_t)s * 64 + b) * 1024 + lane * 16;
    float d = 0.f;
#pragma unroll
    for (int i = 0; i < 4; i++) {
      float4 v = *(const float4*)(cp + i * 4);
      d += v.x * qf[i * 4] + v.y * qf[i * 4 + 1] + v.z * qf[i * 4 + 2] + v.w * qf[i * 4 + 3];
    }
#pragma unroll
    for (int off = 32; off > 0; off >>= 1) d += __shfl_down(d, off, 64);
    if (lane == 0) s_sc[s] = d;
  }
  __syncthreads();
  if (w == 0) {
    float v = s_sc[lane];
    float mx = v;
#pragma unroll
    for (int off = 32; off > 0; off >>= 1) mx = fmaxf(mx, __shfl_xor(mx, off, 64));
    float e = __expf(v - mx);
    float sm = e;
#pragma unroll
    for (int off = 32; off > 0; off >>= 1) sm += __shfl_xor(sm, off, 64);
    float a = e / sm;
    s_at[lane] = a;
    if (t == 63) attn_out[b * 64 + lane] = a;
  }
  __syncthreads();
#pragma unroll
  for (int rep = 0; rep < 4; rep++) {
    int h = rep * 256 + tid;
    float acc = 0.f;
    for (int s = 0; s < 64; s++)
      acc += s_at[s] * ctx[((size_t)s * 64 + b) * 1024 + h];
    wc[(size_t)m * 1024 + h] = (f16)acc;
  }
}

// ---------------------------------------------------------------- launch
extern "C" void kernel_launch(void* const* d_in, const int* in_sizes, int n_in,
                              void* d_out, int out_size, void* d_ws, size_t ws_size,
                              hipStream_t stream) {
  const int*   input = (const int*)d_in[0];
  const float* h0    = (const float*)d_in[1];
  const float* c0    = (const float*)d_in[2];
  const float* ctx   = (const float*)d_in[3];
  const float* emb   = (const float*)d_in[4];
  const float* w_ih  = (const float*)d_in[5];
  const float* w_hh  = (const float*)d_in[6];
  const float* b_ih  = (const float*)d_in[7];
  const float* b_hh  = (const float*)d_in[8];
  const float* w_in  = (const float*)d_in[9];
  const float* w_out = (const float*)d_in[10];
  float* out = (float*)d_out;

  char* ws = (char*)d_ws;
  size_t off = 0;
  auto alloc = [&](size_t bytes) {
    char* p = ws + off;
    off += (bytes + 255) & ~(size_t)255;
    return p;
  };
  f16*   h2hist = (f16*)alloc((size_t)65 * 65536 * 2);     // slot0=init, slot t+1=h2_t
  f16*   h1hist = (f16*)alloc((size_t)65 * 65536 * 2);     // slot0=init, slot t+1=h1_t
  float* Q      = (float*)alloc((size_t)4096 * 1024 * 4);  // f32 for attention accuracy
  f16*   wc     = (f16*)alloc((size_t)4096 * 1024 * 2);
  f16*   xg     = (f16*)alloc((size_t)4096 * 1024 * 2);    // gathered emb rows
  f16*   winh   = (f16*)alloc((size_t)1024 * 1024 * 2);
  f16*   wouth  = (f16*)alloc((size_t)1024 * 2048 * 2);
  unsigned* flags = (unsigned*)alloc(32768);  // 256 flags + 8 go-lines, 64B-padded

  float* outs = out;                              // [T*B][1024]
  float* hf   = out + (size_t)4096 * 1024;        // [2][64][1024]
  float* cf   = hf + 131072;
  float* attn = cf + 131072;                      // [64][64]

  // ---- small weight converts (only the ones still needed by K3/K5) + emb gather
  f2h_kernel<<<1024, 256, 0, stream>>>(w_in, winh);   // 1024*1024
  f2h_kernel<<<2048, 256, 0, stream>>>(w_out, wouth); // 1024*2048
  gather_rows<<<4096, 256, 0, stream>>>(emb, input, xg);
  init_h<<<256, 256, 0, stream>>>(h0, h1hist, h2hist, flags);

  // ---- K2: entire 64-step 2-layer LSTM in ONE cooperative kernel.
  // Weights in LDS; h writes sc1 into write-once history slots; h reads normal
  // cached loads; LEADER-GATHER barrier (block 0 gathers, replicated go-lines).
  {
    void* args[] = {(void*)&w_ih, (void*)&w_hh, (void*)&b_ih, (void*)&b_hh,
                    (void*)&c0, (void*)&xg, (void*)&h1hist, (void*)&h2hist,
                    (void*)&hf, (void*)&cf, (void*)&flags};
    hipLaunchCooperativeKernel(lstm_persistent, dim3(256), dim3(512), args, 0, stream);
  }

  // K3: Q = H2_all @ w_in^T   [M=4096,N=1024,K=1024], f32 out
  gemm_simple<float><<<dim3(16, 64), 256, 0, stream>>>(h2hist + 65536, nullptr,
      winh, nullptr, nullptr, Q, 1024, 1024, 1024, 0);

  // K4: scores -> softmax -> weighted context (+ final-step attention output), all f32
  attn_kernel<<<4096, 256, 0, stream>>>(Q, ctx, wc, attn);

  // K5: outs = tanh([wc | H2_all] @ w_out^T)   [M=4096,N=1024,K=2048], f32 out
  gemm_simple<float><<<dim3(16, 64), 256, 0, stream>>>(wc, h2hist + 65536,
      wouth, nullptr, nullptr, outs, 1024, 1024, 2048, 1);
}

// Round 8
// 1327.136 us; speedup vs baseline: 1.1611x; 1.1611x over previous
//
#include <hip/hip_runtime.h>

typedef _Float16 f16;
typedef __attribute__((ext_vector_type(4))) _Float16 f16x4;
typedef __attribute__((ext_vector_type(8))) _Float16 f16x8;
typedef __attribute__((ext_vector_type(4))) float f32x4;

// ---------------------------------------------------------------- helpers
__device__ __forceinline__ float fast_sig(float x) { return 1.f / (1.f + __expf(-x)); }
// tanh via 1 - 2/(e^{2x}+1): saturates cleanly to +/-1, no NaN at extremes
__device__ __forceinline__ float fast_tanh(float x) {
  float e = __expf(2.f * x);
  return 1.f - 2.f / (e + 1.f);
}

// ---------------------------------------------------------------- f32 -> f16 convert
__global__ __launch_bounds__(256) void f2h_kernel(const float* __restrict__ src,
                                                  f16* __restrict__ dst) {
  size_t i = ((size_t)blockIdx.x * 256 + threadIdx.x) * 4;
  float4 v = *(const float4*)(src + i);
  dst[i + 0] = (f16)v.x;
  dst[i + 1] = (f16)v.y;
  dst[i + 2] = (f16)v.z;
  dst[i + 3] = (f16)v.w;
}

// gather embedding rows: xg[m,:] = (f16)emb[ids[m],:]   (one block per m, H=1024)
__global__ __launch_bounds__(256) void gather_rows(const float* __restrict__ emb,
                                                   const int* __restrict__ ids,
                                                   f16* __restrict__ xg) {
  int m = blockIdx.x;
  int i = threadIdx.x * 4;
  const float* src = emb + (size_t)ids[m] * 1024 + i;
  float4 v = *(const float4*)src;
  f16* d = xg + (size_t)m * 1024 + i;
  d[0] = (f16)v.x; d[1] = (f16)v.y; d[2] = (f16)v.z; d[3] = (f16)v.w;
}

// ---------------------------------------------------------------- h-state init + flag reset
__global__ __launch_bounds__(256) void init_h(const float* __restrict__ h0,
                                              f16* __restrict__ h1slot0,
                                              f16* __restrict__ h2slot0,
                                              unsigned* __restrict__ flags) {
  int i = blockIdx.x * 256 + threadIdx.x;  // grid 256 -> 65536
  h1slot0[i] = (f16)h0[i];
  h2slot0[i] = (f16)h0[65536 + i];
  if (i < 8192) flags[i] = 0;  // 256 block-flags + 8 go-lines, all 64B-padded
}

// ---------------------------------------------------------------- persistent 2-layer LSTM
// One cooperative launch runs all 64 timesteps. 256 blocks x 512 threads (8 waves),
// block p owns hidden units [4p,4p+4) of BOTH layers; 4 weight matrices (128 KB
// f16) staged into LDS once. Phase t = layer1_t + layer2_{t-1}.
// Barrier history (all ~same, per phase): cg::grid.sync 46us is the only outlier;
// atomic-RMW / poll-all / leader-gather all ~13-14.5us total phase. Conclusion:
// protocol is not the cost; the residual is body memory-pipe time + serial
// publish->detect chain + straggler skew. THIS version: LATE-WAIT pipeline —
// publish the flag at phase end, but WAIT for the epoch only after the x-part
// MFMAs of the next phase (x-part depends only on xg, not on the exchanged h).
// Early-finishing blocks overlap their x-part with stragglers' tails.
// h data: writes agent-scope sc1 into WRITE-ONCE history slots (never stale in
// any L2); reads normal cached loads (verified R6/R7).
__global__ __launch_bounds__(512, 1) void lstm_persistent(
    const float* __restrict__ w_ih, const float* __restrict__ w_hh,  // [2][4096][1024] f32
    const float* __restrict__ b_ih, const float* __restrict__ b_hh,  // [2][4096] f32
    const float* __restrict__ c0,                                    // [2][64][1024] f32
    const f16* __restrict__ xg,                                      // [4096][1024] f16
    f16* __restrict__ h1hist,                                        // 65 slots (slot0 = init)
    f16* __restrict__ h2hist,                                        // 65 slots (slot0 = init)
    float* __restrict__ hf, float* __restrict__ cf,                  // [2][64][1024] f32
    unsigned* __restrict__ flags) {  // [256] block-flags + [8] go-lines, stride-16 u32
  __shared__ f16 wlds[65536];               // 4 matrices x 2048 slots x 8 f16 = 128 KB
  __shared__ float red1[2048], red2[2048];  // [wave][16m][16n] partials, 8 KB each
  __shared__ float bsum[32];                // b_ih+b_hh for this block's 16 rows x 2 layers
  const int p = blockIdx.x;
  const int tid = threadIdx.x;
  const int lane = tid & 63, w = tid >> 6;
  const int mt = w & 3, kh = w >> 2;        // wave = (batch-tile, K-half)
  const int am = mt * 16 + (lane & 15);     // A-fragment batch row
  const int kq = (lane >> 4) * 8;

  // ---- one-time staging: 8192 slots / 512 threads = 16 each
  for (int s = tid; s < 8192; s += 512) {
    const int mat = s >> 11, sl = s & 2047;       // mat: 0=Wih1 1=Whh1 2=Wih2 3=Whh2
    const int ln = sl & 63, ks = sl >> 6;
    const int n = ln & 15;                        // n = gate*4 + unit_local
    const int row = (n >> 2) * 1024 + p * 4 + (n & 3) + ((mat >= 2) ? 4096 : 0);
    const int k = ks * 32 + (ln >> 4) * 8;
    const float* src = ((mat & 1) ? w_hh : w_ih) + (size_t)row * 1024 + k;
    float4 v0 = *(const float4*)src;
    float4 v1 = *(const float4*)(src + 4);
    f16x8 hv = {(f16)v0.x, (f16)v0.y, (f16)v0.z, (f16)v0.w,
                (f16)v1.x, (f16)v1.y, (f16)v1.z, (f16)v1.w};
    *(f16x8*)(wlds + (size_t)mat * 16384 + (size_t)sl * 8) = hv;
  }
  if (tid < 32) {
    int l = tid >> 4, n = tid & 15;
    int row = l * 4096 + (n >> 2) * 1024 + p * 4 + (n & 3);
    bsum[tid] = b_ih[row] + b_hh[row];
  }
  float creg;
  {
    int q = tid & 255;
    size_t idx = (size_t)(q >> 2) * 1024 + p * 4 + (q & 3);
    creg = (tid < 256) ? c0[idx] : c0[65536 + idx];
  }
  __syncthreads();

  for (int t = 0; t <= 64; ++t) {
    // clamped addresses so edge phases stay straight-line (MFMA predicated off)
    const int tx = (t < 64) ? t : 63;
    const int t2 = (t > 0) ? t - 1 : 0;
    // per-lane k-base for this wave: k = ks*32 + kq, ks in [kh*16, kh*16+16)
    const f16* xrow  = xg + ((size_t)tx * 64 + am) * 1024 + kh * 512 + kq;
    const f16* hrow  = h1hist + ((size_t)t * 64 + am) * 1024 + kh * 512 + kq;   // h1_{t-1}
    const f16* h2row = h2hist + ((size_t)t2 * 64 + am) * 1024 + kh * 512 + kq;  // h2_{t-2}

    f32x4 acc1 = {0.f, 0.f, 0.f, 0.f};
    f32x4 acc2 = {0.f, 0.f, 0.f, 0.f};

    // ---- (A) x-part: depends only on xg -> runs BEFORE the barrier wait,
    // overlapping straggler blocks still finishing phase t-1.
    if (t < 64) {
#pragma unroll
      for (int i = 0; i < 16; ++i) {
        const int ks = kh * 16 + i;
        f16x8 xv = *(const f16x8*)(xrow + i * 32);
        f16x8 b0 = *(const f16x8*)(wlds + (size_t)ks * 512 + lane * 8);
        acc1 = __builtin_amdgcn_mfma_f32_16x16x32_f16(xv, b0, acc1, 0, 0, 0);
      }
    }

    // ---- (B) LATE WAIT for epoch t (h1hist[t], h2hist[t-1] published)
    if (t > 0) {
      const unsigned epoch = (unsigned)t;
      if (w == 0) {
        if (p == 0) {
          // leader: gather all 256 flags (4 per lane, distinct padded lines)
          for (;;) {
            bool ok = true;
#pragma unroll
            for (int j = 0; j < 4; j++) {
              unsigned v = __hip_atomic_load(flags + (size_t)(lane * 4 + j) * 16,
                                             __ATOMIC_RELAXED, __HIP_MEMORY_SCOPE_AGENT);
              ok &= (v >= epoch);
            }
            if (__all(ok)) break;
            __builtin_amdgcn_s_sleep(1);
          }
          if (lane < 8)
            __hip_atomic_store(flags + 4096 + (size_t)lane * 16, epoch,
                               __ATOMIC_RELAXED, __HIP_MEMORY_SCOPE_AGENT);
        } else {
          const unsigned* go = flags + 4096 + (size_t)(p & 7) * 16;
          for (;;) {
            unsigned v = __hip_atomic_load(go, __ATOMIC_RELAXED,
                                           __HIP_MEMORY_SCOPE_AGENT);
            if (__all(v >= epoch)) break;
            __builtin_amdgcn_s_sleep(1);
          }
        }
      }
      __syncthreads();
    }

    // ---- (C) h-part: normal cached loads (write-once slots -> never stale)
#pragma unroll
    for (int i = 0; i < 16; ++i) {
      const int ks = kh * 16 + i;
      f16x8 hv  = *(const f16x8*)(hrow + i * 32);
      f16x8 h2v = *(const f16x8*)(h2row + i * 32);
      f16x8 b1 = *(const f16x8*)(wlds + 16384 + (size_t)ks * 512 + lane * 8);
      f16x8 b2 = *(const f16x8*)(wlds + 32768 + (size_t)ks * 512 + lane * 8);
      f16x8 b3 = *(const f16x8*)(wlds + 49152 + (size_t)ks * 512 + lane * 8);
      if (t < 64)
        acc1 = __builtin_amdgcn_mfma_f32_16x16x32_f16(hv, b1, acc1, 0, 0, 0);
      if (t > 0) {
        acc2 = __builtin_amdgcn_mfma_f32_16x16x32_f16(hv, b2, acc2, 0, 0, 0);
        acc2 = __builtin_amdgcn_mfma_f32_16x16x32_f16(h2v, b3, acc2, 0, 0, 0);
      }
    }

    if (t < 64) {
#pragma unroll
      for (int q = 0; q < 4; q++)
        red1[w * 256 + ((lane >> 4) * 4 + q) * 16 + (lane & 15)] = acc1[q];
    }
    if (t > 0) {
#pragma unroll
      for (int q = 0; q < 4; q++)
        red2[w * 256 + ((lane >> 4) * 4 + q) * 16 + (lane & 15)] = acc2[q];
    }
    __syncthreads();

    // ---- (D) elementwise: threads 0-255 -> layer1, 256-511 -> layer2
    if (t < 64 && tid < 256) {
      const int b = tid >> 2, ul = tid & 3;
      const int mrow = (b & 15) * 16, mtb = (b >> 4) * 256;
      float g4[4];
#pragma unroll
      for (int g = 0; g < 4; g++) {
        int n = g * 4 + ul;
        g4[g] = red1[mtb + mrow + n] + red1[1024 + mtb + mrow + n] + bsum[n];
      }
      float cn = fast_sig(g4[1]) * creg + fast_sig(g4[0]) * fast_tanh(g4[2]);
      float hn = fast_sig(g4[3]) * fast_tanh(cn);
      creg = cn;
      const int u = p * 4 + ul;
      if (t == 63) {
        hf[(size_t)b * 1024 + u] = hn;
        cf[(size_t)b * 1024 + u] = cn;
      }
      // pack 4 units (ul=0..3, same wave) -> one 8B agent-scope store
      float h1v = __shfl_down(hn, 1, 64);
      float h2s = __shfl_down(hn, 2, 64);
      float h3v = __shfl_down(hn, 3, 64);
      if (ul == 0) {
        union { f16x4 h; unsigned long long u64; } pk;
        pk.h = (f16x4){(f16)hn, (f16)h1v, (f16)h2s, (f16)h3v};
        f16* dst = h1hist + (size_t)(t + 1) * 65536 + (size_t)b * 1024 + p * 4;
        __hip_atomic_store((unsigned long long*)dst, pk.u64,
                           __ATOMIC_RELAXED, __HIP_MEMORY_SCOPE_AGENT);
      }
    }
    if (t > 0 && tid >= 256) {
      const int q = tid & 255;
      const int b = q >> 2, ul = q & 3;
      const int mrow = (b & 15) * 16, mtb = (b >> 4) * 256;
      float g4[4];
#pragma unroll
      for (int g = 0; g < 4; g++) {
        int n = g * 4 + ul;
        g4[g] = red2[mtb + mrow + n] + red2[1024 + mtb + mrow + n] + bsum[16 + n];
      }
      float cn = fast_sig(g4[1]) * creg + fast_sig(g4[0]) * fast_tanh(g4[2]);
      float hn = fast_sig(g4[3]) * fast_tanh(cn);
      creg = cn;
      const int u = p * 4 + ul;
      if (t == 64) {
        hf[65536 + (size_t)b * 1024 + u] = hn;
        cf[65536 + (size_t)b * 1024 + u] = cn;
      }
      float h1v = __shfl_down(hn, 1, 64);
      float h2s = __shfl_down(hn, 2, 64);
      float h3v = __shfl_down(hn, 3, 64);
      if (ul == 0) {
        union { f16x4 h; unsigned long long u64; } pk;
        pk.h = (f16x4){(f16)hn, (f16)h1v, (f16)h2s, (f16)h3v};
        f16* dst = h2hist + (size_t)t * 65536 + (size_t)b * 1024 + p * 4;
        __hip_atomic_store((unsigned long long*)dst, pk.u64,
                           __ATOMIC_RELAXED, __HIP_MEMORY_SCOPE_AGENT);
      }
    }

    // ---- (E) publish only (no wait here; wait is at (B) of next phase).
    if (t < 64) {
      __syncthreads();  // drains every wave's vmcnt -> sc1 h-stores at LLC
      if (w == 0 && lane == 0)
        __hip_atomic_store(flags + (size_t)p * 16, (unsigned)(t + 1),
                           __ATOMIC_RELAXED, __HIP_MEMORY_SCOPE_AGENT);
    }
  }
}

// ---------------------------------------------------------------- LDS-staged GEMM
// C[m,n] = sum_k A[m,k]*B[n,k] (+bias1+bias2)(tanh). A = A1 rows [*,K1] then A2
// for k>=K1. B row-major [N,Ktot], all f16. Block = 64x64 tile, 4 waves.
// Round-0 counters showed the direct-global version at 4.5% MfmaUtil — latency-
// bound on scattered per-lane B-row gathers. Fix: stage B 64x64 chunks in LDS
// ([64][72] pad -> 2-way bank access on fragment reads, free per m136) with
// register prefetch of the next chunk overlapping the current chunk's MFMAs.
template <typename OutT>
__global__ __launch_bounds__(256) void gemm_lds(
    const f16* __restrict__ A1, const f16* __restrict__ A2,
    const f16* __restrict__ Bm,
    const float* __restrict__ bias1, const float* __restrict__ bias2,
    OutT* __restrict__ C, int ldc,
    int K1, int Ktot, int do_tanh) {
  __shared__ f16 bt[64][72];                // 9 KB, +8 f16 pad
  const int tid = threadIdx.x;
  const int lane = tid & 63;
  const int w = tid >> 6;
  const int m0 = blockIdx.y * 64 + w * 16;  // this wave's 16 m-rows
  const int n0 = blockIdx.x * 64;
  const int am = m0 + (lane & 15);
  const int kq = (lane >> 4) * 8;           // quad's k-offset within a 32-chunk
  const int K2 = Ktot - K1;
  const int br = tid >> 2;                  // staging row 0..63
  const int bs = (tid & 3) * 16;            // staging col (f16): 0,16,32,48

  f32x4 acc[4];
#pragma unroll
  for (int j = 0; j < 4; j++) acc[j] = (f32x4){0.f, 0.f, 0.f, 0.f};

  const f16* bsrc = Bm + (size_t)(n0 + br) * Ktot + bs;
  // prologue: prefetch chunk 0 into registers
  f16x8 s0 = *(const f16x8*)(bsrc);
  f16x8 s1 = *(const f16x8*)(bsrc + 8);

  for (int kc = 0; kc < Ktot; kc += 64) {
    __syncthreads();                        // previous chunk's reads done
    *(f16x8*)&bt[br][bs] = s0;
    *(f16x8*)&bt[br][bs + 8] = s1;
    __syncthreads();
    if (kc + 64 < Ktot) {                   // prefetch next chunk (overlaps MFMAs)
      s0 = *(const f16x8*)(bsrc + kc + 64);
      s1 = *(const f16x8*)(bsrc + kc + 64 + 8);
    }
#pragma unroll
    for (int kk = 0; kk < 64; kk += 32) {
      int k = kc + kk + kq;
      f16x8 av;
      if (k < K1)
        av = *(const f16x8*)(A1 + (size_t)am * K1 + k);
      else
        av = *(const f16x8*)(A2 + (size_t)am * K2 + (k - K1));
#pragma unroll
      for (int j = 0; j < 4; j++) {
        f16x8 bv = *(const f16x8*)&bt[j * 16 + (lane & 15)][kk + kq];
        acc[j] = __builtin_amdgcn_mfma_f32_16x16x32_f16(av, bv, acc[j], 0, 0, 0);
      }
    }
  }

  const int r0 = (lane >> 4) * 4;
  const int cc = lane & 15;
#pragma unroll
  for (int j = 0; j < 4; j++) {
    int col = n0 + j * 16 + cc;
    float bv = 0.f;
    if (bias1) bv += bias1[col];
    if (bias2) bv += bias2[col];
#pragma unroll
    for (int q = 0; q < 4; q++) {
      float v = acc[j][q] + bv;
      if (do_tanh) v = fast_tanh(v);
      C[(size_t)(m0 + r0 + q) * ldc + col] = (OutT)v;
    }
  }
}

// ---------------------------------------------------------------- attention scores/softmax/wc
// one block per (t,b): scores[s] = ctx[s,b,:].q ; softmax ; wc = a @ ctx[:,b,:]
__global__ __launch_bounds__(256) void attn_kernel(
    const float* __restrict__ Q,   // [4096][1024] f32
    const float* __restrict__ ctx, // context f32 [S=64][B=64][H=1024]
    f16* __restrict__ wc,          // [4096][1024] f16
    float* __restrict__ attn_out) {// [64][64] (t==63 only)
  const int m = blockIdx.x;
  const int b = m & 63;
  const int t = m >> 6;
  const int tid = threadIdx.x;
  const int lane = tid & 63;
  const int w = tid >> 6;
  __shared__ float s_sc[64];
  __shared__ float s_at[64];

  const float* qp = Q + (size_t)m * 1024 + lane * 16;
  float qf[16];
#pragma unroll
  for (int i = 0; i < 4; i++) {
    float4 v = *(const float4*)(qp + i * 4);
    qf[i * 4 + 0] = v.x; qf[i * 4 + 1] = v.y; qf[i * 4 + 2] = v.z; qf[i * 4 + 3] = v.w;
  }

  // scores: wave w handles s in [w*16, w*16+16)
  for (int si = 0; si < 16; si++) {
    int s = w * 16 + si;
    const float* cp = ctx + ((size_t)s * 64 + b) * 1024 + lane * 16;
    float d = 0.f;
#pragma unroll
    for (int i = 0; i < 4; i++) {
      float4 v = *(const float4*)(cp + i * 4);
      d += v.x * qf[i * 4] + v.y * qf[i * 4 + 1] + v.z * qf[i * 4 + 2] + v.w * qf[i * 4 + 3];
    }
#pragma unroll
    for (int off = 32; off > 0; off >>= 1) d += __shfl_down(d, off, 64);
    if (lane == 0) s_sc[s] = d;
  }
  __syncthreads();
  if (w == 0) {
    float v = s_sc[lane];
    float mx = v;
#pragma unroll
    for (int off = 32; off > 0; off >>= 1) mx = fmaxf(mx, __shfl_xor(mx, off, 64));
    float e = __expf(v - mx);
    float sm = e;
#pragma unroll
    for (int off = 32; off > 0; off >>= 1) sm += __shfl_xor(sm, off, 64);
    float a = e / sm;
    s_at[lane] = a;
    if (t == 63) attn_out[b * 64 + lane] = a;
  }
  __syncthreads();
#pragma unroll
  for (int rep = 0; rep < 4; rep++) {
    int h = rep * 256 + tid;
    float acc = 0.f;
    for (int s = 0; s < 64; s++)
      acc += s_at[s] * ctx[((size_t)s * 64 + b) * 1024 + h];
    wc[(size_t)m * 1024 + h] = (f16)acc;
  }
}

// ---------------------------------------------------------------- launch
extern "C" void kernel_launch(void* const* d_in, const int* in_sizes, int n_in,
                              void* d_out, int out_size, void* d_ws, size_t ws_size,
                              hipStream_t stream) {
  const int*   input = (const int*)d_in[0];
  const float* h0    = (const float*)d_in[1];
  const float* c0    = (const float*)d_in[2];
  const float* ctx   = (const float*)d_in[3];
  const float* emb   = (const float*)d_in[4];
  const float* w_ih  = (const float*)d_in[5];
  const float* w_hh  = (const float*)d_in[6];
  const float* b_ih  = (const float*)d_in[7];
  const float* b_hh  = (const float*)d_in[8];
  const float* w_in  = (const float*)d_in[9];
  const float* w_out = (const float*)d_in[10];
  float* out = (float*)d_out;

  char* ws = (char*)d_ws;
  size_t off = 0;
  auto alloc = [&](size_t bytes) {
    char* p = ws + off;
    off += (bytes + 255) & ~(size_t)255;
    return p;
  };
  f16*   h2hist = (f16*)alloc((size_t)65 * 65536 * 2);     // slot0=init, slot t+1=h2_t
  f16*   h1hist = (f16*)alloc((size_t)65 * 65536 * 2);     // slot0=init, slot t+1=h1_t
  float* Q      = (float*)alloc((size_t)4096 * 1024 * 4);  // f32 for attention accuracy
  f16*   wc     = (f16*)alloc((size_t)4096 * 1024 * 2);
  f16*   xg     = (f16*)alloc((size_t)4096 * 1024 * 2);    // gathered emb rows
  f16*   winh   = (f16*)alloc((size_t)1024 * 1024 * 2);
  f16*   wouth  = (f16*)alloc((size_t)1024 * 2048 * 2);
  unsigned* flags = (unsigned*)alloc(32768);  // 256 flags + 8 go-lines, 64B-padded

  float* outs = out;                              // [T*B][1024]
  float* hf   = out + (size_t)4096 * 1024;        // [2][64][1024]
  float* cf   = hf + 131072;
  float* attn = cf + 131072;                      // [64][64]

  // ---- small weight converts (only the ones still needed by K3/K5) + emb gather
  f2h_kernel<<<1024, 256, 0, stream>>>(w_in, winh);   // 1024*1024
  f2h_kernel<<<2048, 256, 0, stream>>>(w_out, wouth); // 1024*2048
  gather_rows<<<4096, 256, 0, stream>>>(emb, input, xg);
  init_h<<<256, 256, 0, stream>>>(h0, h1hist, h2hist, flags);

  // ---- K2: entire 64-step 2-layer LSTM in ONE cooperative kernel.
  // Weights in LDS; h via sc1 writes to write-once slots + cached reads;
  // LATE-WAIT leader-gather barrier (publish at phase end, wait after x-part).
  {
    void* args[] = {(void*)&w_ih, (void*)&w_hh, (void*)&b_ih, (void*)&b_hh,
                    (void*)&c0, (void*)&xg, (void*)&h1hist, (void*)&h2hist,
                    (void*)&hf, (void*)&cf, (void*)&flags};
    hipLaunchCooperativeKernel(lstm_persistent, dim3(256), dim3(512), args, 0, stream);
  }

  // K3: Q = H2_all @ w_in^T   [M=4096,N=1024,K=1024], f32 out
  gemm_lds<float><<<dim3(16, 64), 256, 0, stream>>>(h2hist + 65536, nullptr,
      winh, nullptr, nullptr, Q, 1024, 1024, 1024, 0);

  // K4: scores -> softmax -> weighted context (+ final-step attention output), all f32
  attn_kernel<<<4096, 256, 0, stream>>>(Q, ctx, wc, attn);

  // K5: outs = tanh([wc | H2_all] @ w_out^T)   [M=4096,N=1024,K=2048], f32 out
  gemm_lds<float><<<dim3(16, 64), 256, 0, stream>>>(wc, h2hist + 65536,
      wouth, nullptr, nullptr, outs, 1024, 1024, 2048, 1);
}